// Round 15
// baseline (12482.038 us; speedup 1.0000x reference)
//
#include <hip/hip_runtime.h>
#include <cstdint>
#include <math.h>

typedef unsigned int u32;
typedef unsigned long long u64;
typedef double d4 __attribute__((ext_vector_type(4)));

#define TF_PARTITIONABLE 1

#define NU 6144
#define NB 32
#define NTOT (NU * NB)      // 196608
#define NWORD 96            // u64 words per sample row
#define NCH 16              // split-K chunks per GEMM (grid 1536 = 6 blocks/CU)
#define CHK 384             // k per chunk; 6 u64 words per row-chunk
#define NT_TILES 12         // CHK / 32 (even)
#define HALF_BIG 98304u
#define HALF_SMALL 16u

struct Key { u32 a, b; };
struct UVec { float u[NB]; };

// ---------------- threefry2x32 (20 rounds), matches jax._src.prng ----------------
__host__ __device__ __forceinline__ void tf2x32(u32 k0, u32 k1, u32 x0, u32 x1, u32& o0, u32& o1) {
  const u32 k2 = k0 ^ k1 ^ 0x1BD11BDAu;
#define TFR(r) { x0 += x1; x1 = (x1 << r) | (x1 >> (32 - r)); x1 ^= x0; }
  x0 += k0; x1 += k1;
  TFR(13) TFR(15) TFR(26) TFR(6)  x0 += k1; x1 += k2 + 1u;
  TFR(17) TFR(29) TFR(16) TFR(24) x0 += k2; x1 += k0 + 2u;
  TFR(13) TFR(15) TFR(26) TFR(6)  x0 += k0; x1 += k1 + 3u;
  TFR(17) TFR(29) TFR(16) TFR(24) x0 += k1; x1 += k2 + 4u;
  TFR(13) TFR(15) TFR(26) TFR(6)  x0 += k2; x1 += k0 + 5u;
#undef TFR
  o0 = x0; o1 = x1;
}

__host__ __device__ __forceinline__ u32 rbits(u32 k0, u32 k1, u32 t, u32 half) {
#if TF_PARTITIONABLE
  (void)half;
  u32 a, b; tf2x32(k0, k1, 0u, t, a, b); return a ^ b;
#else
  u32 a, b;
  if (t < half) { tf2x32(k0, k1, t, half + t, a, b); return a; }
  tf2x32(k0, k1, t - half, t, a, b); return b;
#endif
}

__host__ __device__ __forceinline__ float u01f(u32 bits) {
  union { u32 u; float f; } c; c.u = (bits >> 9) | 0x3f800000u;
  return c.f - 1.0f;
}

// ---------------- MFMA f64 layout self-calibration ----------------
__device__ __forceinline__ double pav(int probe, int l) {
  return probe ? (double)(((l * 13 + 5) & 63) + 1) : (double)(l + 1);
}
__device__ __forceinline__ double pbv(int probe, int l) {
  return probe ? (double)(((l * 11 + 2) & 63) + 1) : (double)(((l * 7 + 3) & 63) + 1);
}

// tbl[lane*16 + {0..8}] = mA,kA,nB,kB,bD0,bDs,jD0,jDs,ok
__global__ __launch_bounds__(64) void k_calib(int* __restrict__ tbl) {
  int L = threadIdx.x;
  d4 z = {0.0, 0.0, 0.0, 0.0};
  d4 o0 = __builtin_amdgcn_mfma_f64_16x16x4f64(pav(0, L), pbv(0, L), z, 0, 0, 0);
  d4 o1 = __builtin_amdgcn_mfma_f64_16x16x4f64(pav(1, L), pbv(1, L), z, 0, 0, 0);
  int q = L >> 4, m16 = L & 15;
  int best = -1;
  for (int combo = 0; combo < 16; ++combo) {
    int fa = combo & 1, fb = (combo >> 1) & 1, fd = combo >> 2;
    int ok = 1;
    for (int probe = 0; probe < 2; ++probe) {
#pragma unroll
      for (int r = 0; r < 4; ++r) {
        int i, j;
        if (fd == 0)      { j = m16; i = 4 * q + r; }
        else if (fd == 1) { j = m16; i = q + 4 * r; }
        else if (fd == 2) { i = m16; j = 4 * q + r; }
        else              { i = m16; j = q + 4 * r; }
        double pred = 0.0;
#pragma unroll
        for (int k = 0; k < 4; ++k) {
          int la = fa ? (i * 4 + k) : (k * 16 + i);
          int lb = fb ? (j * 4 + k) : (k * 16 + j);
          pred += pav(probe, la) * pbv(probe, lb);
        }
        double obs = probe ? (r == 0 ? o1[0] : r == 1 ? o1[1] : r == 2 ? o1[2] : o1[3])
                           : (r == 0 ? o0[0] : r == 1 ? o0[1] : r == 2 ? o0[2] : o0[3]);
        if (pred != obs) ok = 0;
      }
    }
    if (__all(ok) && best < 0) best = combo;
  }
  int mA = 0, kA = 0, nB = 0, kB = 0, b0_ = 0, bs = 0, j0 = 0, js = 0, okf = 0;
  if (best >= 0) {
    int fa = best & 1, fb = (best >> 1) & 1, fd = best >> 2;
    if (fa) { mA = L >> 2; kA = L & 3; } else { mA = m16; kA = q; }
    if (fb) { nB = L >> 2; kB = L & 3; } else { nB = m16; kB = q; }
    if (fd == 0)      { j0 = m16; js = 0; b0_ = 4 * q; bs = 1; }
    else if (fd == 1) { j0 = m16; js = 0; b0_ = q; bs = 4; }
    else if (fd == 2) { b0_ = m16; bs = 0; j0 = 4 * q; js = 1; }
    else              { b0_ = m16; bs = 0; j0 = q; js = 4; }
    okf = 1;
  }
  int* p = tbl + L * 16;
  p[0] = mA; p[1] = kA; p[2] = nB; p[3] = kB;
  p[4] = b0_; p[5] = bs; p[6] = j0; p[7] = js; p[8] = okf;
}

// ---------------- control kernels ----------------
__global__ void k_init(u32* __restrict__ a, u32* __restrict__ b) { *a = 0u; *b = 0u; }

__global__ void k_allconv(const u32* __restrict__ conv, u32* __restrict__ skipc) {
  if (*skipc) return;
  u32 all = 1u;
  for (int b = 0; b < NB; ++b) all &= conv[b];
  if (all) *skipc = 1u;
}

// ---------------- state init (bit-packed only; states live in pk) ----------------
__global__ __launch_bounds__(256) void k_pos_v(const float* __restrict__ vin, u64* __restrict__ pk) {
  int tid = blockIdx.x * 256 + threadIdx.x;          // 24576 = 32*768
  int b = tid / 768, p = tid % 768;
  float x = vin[tid];
  int q = (int)floorf(x * 256.0f);
  q = q < 0 ? 0 : (q > 255 ? 255 : q);
  ((unsigned char*)pk)[b * 768 + p] = (unsigned char)q;   // byte == 8 LSB-first bits
}

__global__ __launch_bounds__(256) void k_bern(u32 k0, u32 k1, u64* __restrict__ pk) {
  int tid = blockIdx.x * 256 + threadIdx.x;          // 196608
  bool s = u01f(rbits(k0, k1, (u32)tid, HALF_BIG)) < 0.5f;
  u64 m = __ballot(s);
  if ((threadIdx.x & 63) == 0) pk[tid >> 6] = m;
}

// fused proposal generator for coupling (2 or 3 states, one dispatch)
__global__ __launch_bounds__(256) void k_bern3(u32 has_v, u32 va, u32 vb, u32 ha0, u32 hb0,
                                               u32 ha1, u32 hb1,
                                               u64* __restrict__ pkv, u64* __restrict__ pkh0,
                                               u64* __restrict__ pkh1, const u32* __restrict__ skip) {
  if (skip && *skip) return;
  int tid = blockIdx.x * 256 + threadIdx.x;
  int lane0 = (threadIdx.x & 63) == 0;
  if (has_v) {
    bool s = u01f(rbits(va, vb, (u32)tid, HALF_BIG)) < 0.5f;
    u64 m = __ballot(s);
    if (lane0) pkv[tid >> 6] = m;
  }
  { bool s = u01f(rbits(ha0, hb0, (u32)tid, HALF_BIG)) < 0.5f;
    u64 m = __ballot(s);
    if (lane0) pkh0[tid >> 6] = m; }
  { bool s = u01f(rbits(ha1, hb1, (u32)tid, HALF_BIG)) < 0.5f;
    u64 m = __ballot(s);
    if (lane0) pkh1[tid >> 6] = m; }
}

// ---------------- sampling ----------------
__device__ __forceinline__ bool samp_dec(float f, int t1, u32 k0, u32 k1, u32 tid) {
  if (t1) {
    double u = (double)u01f(rbits(k0, k1, tid, HALF_BIG));
    return u < 1.0 / (1.0 + exp(-(double)f));
  }
  return f >= 0.0f;
}

// merged sample over even mask (T=1 gibbs merges); writes pk only
__global__ __launch_bounds__(256) void k_samp(const float* __restrict__ fE, const float* __restrict__ fO,
                                              u32 even, int t1, u32 k0, u32 k1,
                                              u64* __restrict__ pk) {
  int tid = blockIdx.x * 256 + threadIdx.x;
  int b = tid / NU;
  float f = ((even >> b) & 1u) ? fE[tid] : fO[tid];
  bool s = samp_dec(f, t1, k0, k1, (u32)tid);
  u64 m = __ballot(s);
  if ((threadIdx.x & 63) == 0) pk[tid >> 6] = m;
}

// ---------------- GEMM kernels: barrier-free, LDS-free; 4 MFMA chains/wave ----------------
// out[b][j] = sum_k x[k][b] * W[k][j]  (x @ W).  k(slot kappa, step u) = base + kappa + 4u.
__global__ __launch_bounds__(256) void k_gemm_n(const float* __restrict__ W, const u64* __restrict__ pkx,
                                                double* __restrict__ part, const u32* __restrict__ skip,
                                                const int* __restrict__ tbl) {
  if (skip && *skip) return;
  int jt = blockIdx.x % 96, c = blockIdx.x / 96;     // grid 96*NCH
  int wid = threadIdx.x >> 6, lane = threadIdx.x & 63;
  int kbase = c * CHK;
  int jn0 = jt * 64;
  const int* tp = tbl + lane * 16;
  if (tp[8]) {
    int mA = tp[0], kA = tp[1], nB = tp[2], kB = tp[3];
    int bD0 = tp[4], bDs = tp[5], jD0 = tp[6], jDs = tp[7];
    d4 a0e = {0.0, 0.0, 0.0, 0.0}, a0o = {0.0, 0.0, 0.0, 0.0};
    d4 a1e = {0.0, 0.0, 0.0, 0.0}, a1o = {0.0, 0.0, 0.0, 0.0};
    const u64* px0 = pkx + (size_t)mA * NWORD + (kbase >> 6);
    const u64* px1 = pkx + (size_t)(mA + 16) * NWORD + (kbase >> 6);
    const float* wb = W + (size_t)(kbase + kB) * NU + jn0 + wid * 16 + nB;
    float cur0[8], cur1[8], nxt0[8], nxt1[8];
#pragma unroll
    for (int u = 0; u < 8; ++u) {
      cur0[u] = wb[(size_t)(4 * u) * NU];
      cur1[u] = wb[(size_t)(32 + 4 * u) * NU];
    }
    for (int t2 = 0; t2 < NT_TILES; t2 += 2) {
      if (t2 + 2 < NT_TILES) {
        const float* wn = wb + (size_t)((t2 + 2) * 32) * NU;
#pragma unroll
        for (int u = 0; u < 8; ++u) {
          nxt0[u] = wn[(size_t)(4 * u) * NU];
          nxt1[u] = wn[(size_t)(32 + 4 * u) * NU];
        }
      }
      u64 ww0 = px0[t2 >> 1], ww1 = px1[t2 >> 1];
      u32 e0 = (u32)(ww0 >> kA),        e1 = (u32)(ww1 >> kA);
      u32 o0 = (u32)(ww0 >> (32 + kA)), o1 = (u32)(ww1 >> (32 + kA));
#pragma unroll
      for (int u = 0; u < 8; ++u) {
        double wv = (double)cur0[u];
        a0e = __builtin_amdgcn_mfma_f64_16x16x4f64((double)((e0 >> (4 * u)) & 1u), wv, a0e, 0, 0, 0);
        a1e = __builtin_amdgcn_mfma_f64_16x16x4f64((double)((e1 >> (4 * u)) & 1u), wv, a1e, 0, 0, 0);
      }
#pragma unroll
      for (int u = 0; u < 8; ++u) {
        double wv = (double)cur1[u];
        a0o = __builtin_amdgcn_mfma_f64_16x16x4f64((double)((o0 >> (4 * u)) & 1u), wv, a0o, 0, 0, 0);
        a1o = __builtin_amdgcn_mfma_f64_16x16x4f64((double)((o1 >> (4 * u)) & 1u), wv, a1o, 0, 0, 0);
      }
#pragma unroll
      for (int u = 0; u < 8; ++u) { cur0[u] = nxt0[u]; cur1[u] = nxt1[u]; }
    }
    d4 acc0, acc1;
#pragma unroll
    for (int r = 0; r < 4; ++r) { acc0[r] = a0e[r] + a0o[r]; acc1[r] = a1e[r] + a1o[r]; }
    int jn = jn0 + wid * 16;
    double* pp = part + (size_t)c * NTOT + jn;
#pragma unroll
    for (int r = 0; r < 4; ++r) {
      int bi = bD0 + bDs * r, jj = jD0 + jDs * r;
      pp[(size_t)bi * NU + jj] = acc0[r];
      pp[(size_t)(bi + 16) * NU + jj] = acc1[r];
    }
  } else {
    // LDS-free VALU fallback (dead path): wave wid = batch group (8 b), full chunk
    int j = jn0 + lane;
    const float* wp = W + (size_t)kbase * NU + j;
    double acc[8];
#pragma unroll
    for (int b = 0; b < 8; ++b) acc[b] = 0.0;
    for (int i = 0; i < CHK; ++i) {
      double w = (double)wp[(size_t)i * NU];
      int k = kbase + i;
#pragma unroll
      for (int b = 0; b < 8; ++b) {
        double xb = (double)((pkx[(size_t)(wid * 8 + b) * NWORD + (k >> 6)] >> (k & 63)) & 1ull);
        acc[b] = fma(xb, w, acc[b]);
      }
    }
    double* pp = part + (size_t)c * NTOT + j;
#pragma unroll
    for (int b = 0; b < 8; ++b) pp[(size_t)(wid * 8 + b) * NU] = acc[b];
  }
}

// out[b][j] = sum_k x[k][b] * W[j][k]  (x @ W.T).  k(slot kappa, step u) = base + kappa*8 + u.
__global__ __launch_bounds__(256) void k_gemm_t(const float* __restrict__ W, const u64* __restrict__ pkx,
                                                double* __restrict__ part, const u32* __restrict__ skip,
                                                const int* __restrict__ tbl) {
  if (skip && *skip) return;
  int jt = blockIdx.x % 96, c = blockIdx.x / 96;
  int wid = threadIdx.x >> 6, lane = threadIdx.x & 63;
  int kbase = c * CHK;
  int jn0 = jt * 64;
  const int* tp = tbl + lane * 16;
  if (tp[8]) {
    int mA = tp[0], kA = tp[1], nB = tp[2], kB = tp[3];
    int bD0 = tp[4], bDs = tp[5], jD0 = tp[6], jDs = tp[7];
    d4 a0e = {0.0, 0.0, 0.0, 0.0}, a0o = {0.0, 0.0, 0.0, 0.0};
    d4 a1e = {0.0, 0.0, 0.0, 0.0}, a1o = {0.0, 0.0, 0.0, 0.0};
    const u64* px0 = pkx + (size_t)mA * NWORD + (kbase >> 6);
    const u64* px1 = pkx + (size_t)(mA + 16) * NWORD + (kbase >> 6);
    const float* wb = W + (size_t)(jn0 + wid * 16 + nB) * NU + kbase + kB * 8;
    float4 c0a = *(const float4*)(wb);
    float4 c0b = *(const float4*)(wb + 4);
    float4 c1a = *(const float4*)(wb + 32);
    float4 c1b = *(const float4*)(wb + 36);
    for (int t2 = 0; t2 < NT_TILES; t2 += 2) {
      float4 n0a, n0b, n1a, n1b;
      if (t2 + 2 < NT_TILES) {
        const float* wn = wb + (t2 + 2) * 32;
        n0a = *(const float4*)(wn);
        n0b = *(const float4*)(wn + 4);
        n1a = *(const float4*)(wn + 32);
        n1b = *(const float4*)(wn + 36);
      }
      u64 ww0 = px0[t2 >> 1], ww1 = px1[t2 >> 1];
      u32 e0 = (u32)(ww0 >> (kA * 8)),        e1 = (u32)(ww1 >> (kA * 8));
      u32 o0 = (u32)(ww0 >> (32 + kA * 8)),   o1 = (u32)(ww1 >> (32 + kA * 8));
      {
        float fr0 = c0a.x, fr1 = c0a.y, fr2 = c0a.z, fr3 = c0a.w;
        float fr4 = c0b.x, fr5 = c0b.y, fr6 = c0b.z, fr7 = c0b.w;
#pragma unroll
        for (int u = 0; u < 8; ++u) {
          float fv = (u == 0) ? fr0 : (u == 1) ? fr1 : (u == 2) ? fr2 : (u == 3) ? fr3
                   : (u == 4) ? fr4 : (u == 5) ? fr5 : (u == 6) ? fr6 : fr7;
          double wv = (double)fv;
          a0e = __builtin_amdgcn_mfma_f64_16x16x4f64((double)((e0 >> u) & 1u), wv, a0e, 0, 0, 0);
          a1e = __builtin_amdgcn_mfma_f64_16x16x4f64((double)((e1 >> u) & 1u), wv, a1e, 0, 0, 0);
        }
      }
      {
        float fr0 = c1a.x, fr1 = c1a.y, fr2 = c1a.z, fr3 = c1a.w;
        float fr4 = c1b.x, fr5 = c1b.y, fr6 = c1b.z, fr7 = c1b.w;
#pragma unroll
        for (int u = 0; u < 8; ++u) {
          float fv = (u == 0) ? fr0 : (u == 1) ? fr1 : (u == 2) ? fr2 : (u == 3) ? fr3
                   : (u == 4) ? fr4 : (u == 5) ? fr5 : (u == 6) ? fr6 : fr7;
          double wv = (double)fv;
          a0o = __builtin_amdgcn_mfma_f64_16x16x4f64((double)((o0 >> u) & 1u), wv, a0o, 0, 0, 0);
          a1o = __builtin_amdgcn_mfma_f64_16x16x4f64((double)((o1 >> u) & 1u), wv, a1o, 0, 0, 0);
        }
      }
      c0a = n0a; c0b = n0b; c1a = n1a; c1b = n1b;
    }
    d4 acc0, acc1;
#pragma unroll
    for (int r = 0; r < 4; ++r) { acc0[r] = a0e[r] + a0o[r]; acc1[r] = a1e[r] + a1o[r]; }
    int jn = jn0 + wid * 16;
    double* pp = part + (size_t)c * NTOT + jn;
#pragma unroll
    for (int r = 0; r < 4; ++r) {
      int bi = bD0 + bDs * r, jj = jD0 + jDs * r;
      pp[(size_t)bi * NU + jj] = acc0[r];
      pp[(size_t)(bi + 16) * NU + jj] = acc1[r];
    }
  } else {
    // LDS-free VALU fallback (dead path): wave wid = batch group, scalar W[j][k] reads
    int j = jn0 + lane;
    const float* wp = W + (size_t)j * NU + kbase;
    double acc[8];
#pragma unroll
    for (int b = 0; b < 8; ++b) acc[b] = 0.0;
    for (int i = 0; i < CHK; ++i) {
      double w = (double)wp[i];
      int k = kbase + i;
#pragma unroll
      for (int b = 0; b < 8; ++b) {
        double xb = (double)((pkx[(size_t)(wid * 8 + b) * NWORD + (k >> 6)] >> (k & 63)) & 1ull);
        acc[b] = fma(xb, w, acc[b]);
      }
    }
    double* pp = part + (size_t)c * NTOT + j;
#pragma unroll
    for (int b = 0; b < 8; ++b) pp[(size_t)(wid * 8 + b) * NU] = acc[b];
  }
}

// ---------------- reduce (+ optional fused sample) ----------------
__global__ __launch_bounds__(256) void k_reduce(const double* __restrict__ part, const float* __restrict__ bias,
                                                const float* __restrict__ src, float* __restrict__ out,
                                                const u32* __restrict__ skip) {
  if (skip && *skip) return;
  int tid = blockIdx.x * 256 + threadIdx.x;
  int j = tid % NU;
  double s = src ? (double)src[tid] : 0.0;
  if (bias) s += (double)bias[j];
#pragma unroll
  for (int c = 0; c < NCH; ++c) s += part[(size_t)c * NTOT + tid];
  out[tid] = (float)s;
}

// reduce -> (optional out); sample into pk for batch rows in wmask
__global__ __launch_bounds__(256) void k_redsamp(const double* __restrict__ part, const float* __restrict__ bias,
                                                 const float* __restrict__ src, float* __restrict__ out,
                                                 int t1, u32 k0, u32 k1,
                                                 u64* __restrict__ pk,
                                                 const u32* __restrict__ skip, u32 wmask) {
  if (skip && *skip) return;
  int tid = blockIdx.x * 256 + threadIdx.x;
  int j = tid % NU, b = tid / NU;
  double s = src ? (double)src[tid] : 0.0;
  if (bias) s += (double)bias[j];
#pragma unroll
  for (int c = 0; c < NCH; ++c) s += part[(size_t)c * NTOT + tid];
  float f = (float)s;
  if (out) out[tid] = f;
  bool wr = (wmask >> b) & 1u;
  bool smp = samp_dec(f, t1, k0, k1, (u32)tid);
  u64 m = __ballot(smp);
  if (((threadIdx.x & 63) == 0) && wr) pk[tid >> 6] = m;
  (void)j;
}

// ---------------- energy / accept / merge ----------------
__global__ __launch_bounds__(256) void k_energy(const u64* __restrict__ pkv, const u64* __restrict__ pkh0,
                                                const u64* __restrict__ pkh1, const float* __restrict__ f1,
                                                const float* __restrict__ f2, const float* __restrict__ b0,
                                                float* __restrict__ eout, const u32* __restrict__ skip) {
  if (skip && *skip) return;
  __shared__ double red[256];
  int b = blockIdx.x, t = threadIdx.x;
  double s = 0.0;
  for (int j = t; j < NU; j += 256) {
    int w = j >> 6, bit = j & 63;
    if ((pkv [b * NWORD + w] >> bit) & 1ull) s += (double)b0[j];
    if ((pkh0[b * NWORD + w] >> bit) & 1ull) s += (double)f1[(size_t)b * NU + j];
    if ((pkh1[b * NWORD + w] >> bit) & 1ull) s += (double)f2[(size_t)b * NU + j];
  }
  red[t] = s; __syncthreads();
  for (int off = 128; off > 0; off >>= 1) { if (t < off) red[t] += red[t + off]; __syncthreads(); }
  if (t == 0) eout[b] = (float)(-red[0]);
}

__global__ __launch_bounds__(64) void k_accept(float* __restrict__ ecur, const float* __restrict__ eprop,
                                               float* __restrict__ erun, u32* __restrict__ conv,
                                               u32* __restrict__ accf,
                                               const u64* __restrict__ pv, const u64* __restrict__ pcv,
                                               const u64* __restrict__ ph0, const u64* __restrict__ pch0,
                                               const u64* __restrict__ ph1, const u64* __restrict__ pch1,
                                               UVec uv, int first, const u32* __restrict__ skip) {
  if (skip && *skip) return;
  int b = blockIdx.x, t = threadIdx.x;
  u64 diff = 0ull;
  for (int w = t; w < NWORD; w += 64) {
    size_t o = (size_t)b * NWORD + w;
    if (pv) diff |= pv[o] ^ pcv[o];
    diff |= ph0[o] ^ pch0[o];
    diff |= ph1[o] ^ pch1[o];
  }
  int neq = __any(diff != 0ull);
  if (t == 0) {
    float ec = ecur[b], ep = eprop[b];
    bool acc = (double)uv.u[b] < exp(fmin((double)ec - (double)ep, 0.0));
    bool m = first ? true : (conv[b] == 0u);
    bool upd = m && acc;
    if (first) erun[b] = acc ? ep : ec;
    else if (upd) erun[b] += (ep - ec);
    if (upd) ecur[b] = ep;
    u32 c2 = acc ? (neq ? 0u : 1u) : 1u;
    conv[b] = first ? c2 : (conv[b] | c2);
    accf[b] = upd ? 1u : 0u;
  }
}

__global__ __launch_bounds__(256) void k_merge_pk(const u32* __restrict__ accf,
                                                  const u64* __restrict__ pa, u64* __restrict__ ca,
                                                  const u64* __restrict__ pb, u64* __restrict__ cb,
                                                  const u64* __restrict__ pc, u64* __restrict__ cc,
                                                  const u32* __restrict__ skip) {
  if (skip && *skip) return;
  int w = blockIdx.x * 256 + threadIdx.x;
  if (w >= NB * NWORD) return;
  int b = w / NWORD;
  if (accf[b]) {
    ca[w] = pa[w];
    cb[w] = pb[w];
    if (pc) cc[w] = pc[w];
  }
}

__global__ void k_final(const float* __restrict__ ep, const float* __restrict__ en, float* __restrict__ out) {
  int b = threadIdx.x;
  if (b < NB) out[b] = ep[b] - en[b];
}

// ---------------- host-side key derivation ----------------
static void split_keys(Key k, int n, Key* out) {
#if TF_PARTITIONABLE
  for (int i = 0; i < n; ++i) { u32 a, b; tf2x32(k.a, k.b, 0u, (u32)i, a, b); out[i].a = a; out[i].b = b; }
#else
  u32 flat[64];
  for (int i = 0; i < n; ++i) { u32 a, b; tf2x32(k.a, k.b, (u32)i, (u32)(n + i), a, b); flat[i] = a; flat[n + i] = b; }
  for (int i = 0; i < n; ++i) { out[i].a = flat[2 * i]; out[i].b = flat[2 * i + 1]; }
#endif
}
static u32 mask32(Key k) {
  u32 m = 0;
  for (int b = 0; b < NB; ++b)
    if (u01f(rbits(k.a, k.b, (u32)b, HALF_SMALL)) < 0.5f) m |= (1u << b);
  return m;
}

extern "C" void kernel_launch(void* const* d_in, const int* in_sizes, int n_in,
                              void* d_out, int out_size, void* d_ws, size_t ws_size,
                              hipStream_t stream) {
  const float* vin = (const float*)d_in[0];
  const float* W0  = (const float*)d_in[1];
  const float* W1  = (const float*)d_in[2];
  const float* b0  = (const float*)d_in[3];
  const float* b1  = (const float*)d_in[4];
  const float* b2  = (const float*)d_in[5];
  float* outp = (float*)d_out;

  // ---- workspace layout (~31 MB) ----
  char* ws = (char*)d_ws;
  size_t off = 0;
  auto alloc = [&](size_t bytes) -> void* {
    void* p = ws + off; off += (bytes + 255) & ~(size_t)255; return p;
  };
  enum { SV = 0, SH0, SH1, SVE, SH1E, SH0O, SVP, SH0P, SH1P, NS };
  enum { IV = 0, IA, IB, IC, ID, IE, IF2, NF };
  u64* PK[NS]; float* F[NF];
  for (int f = 0; f < NF; ++f) F[f] = (float*)alloc((size_t)NTOT * 4);
  double* PART = (double*)alloc((size_t)NCH * NTOT * 8);
  for (int s = 0; s < NS; ++s) PK[s] = (u64*)alloc((size_t)NB * NWORD * 8);
  int*   TBL    = (int*)alloc(64 * 16 * 4);
  float* E_CUR  = (float*)alloc(256);
  float* E_PROP = (float*)alloc(256);
  float* E_POS  = (float*)alloc(256);
  float* E_NEG  = (float*)alloc(256);
  u32*   ACC    = (u32*)alloc(256);
  u32*   CONV   = (u32*)alloc(256);
  u32*   SKIPC  = (u32*)alloc(256);
  u32*   DUMMY  = (u32*)alloc(256);
  if (off > ws_size) return;

  // ---- host RNG: full key tree from jax.random.key(42) ----
  Key root{0u, 42u};
  Key ks[13]; split_keys(root, 13, ks);
  const Key KZ{0u, 0u};

  // ---- MFMA layout calibration (deterministic, graph-safe) ----
  k_calib<<<dim3(1), dim3(64), 0, stream>>>(TBL);

  // ---- launch helpers ----
  auto GEMM_T = [&](const float* Wm, int xs, const u32* skip) {
    k_gemm_t<<<dim3(96 * NCH), dim3(256), 0, stream>>>(Wm, PK[xs], PART, skip, TBL);
  };
  auto GEMM_N = [&](const float* Wm, int xs, const u32* skip) {
    k_gemm_n<<<dim3(96 * NCH), dim3(256), 0, stream>>>(Wm, PK[xs], PART, skip, TBL);
  };
  auto RED = [&](const float* bias, const float* src, float* dst, const u32* skip) {
    k_reduce<<<dim3(768), dim3(256), 0, stream>>>(PART, bias, src, dst, skip);
  };
  auto REDS = [&](const float* bias, const float* src, float* dst, int t1, Key k, int sdst,
                  const u32* skip, u32 wm) {
    k_redsamp<<<dim3(768), dim3(256), 0, stream>>>(PART, bias, src, dst, t1, k.a, k.b,
                                                   PK[sdst], skip, wm);
  };
  auto GT = [&](const float* Wm, int xs, const float* bias, const float* src, float* dst, const u32* skip) {
    GEMM_T(Wm, xs, skip); RED(bias, src, dst, skip);
  };
  auto GN = [&](const float* Wm, int xs, const float* bias, const float* src, float* dst, const u32* skip) {
    GEMM_N(Wm, xs, skip); RED(bias, src, dst, skip);
  };
  auto GTS = [&](const float* Wm, int xs, const float* bias, const float* src, float* dst,
                 int t1, Key k, int sdst, const u32* skip) {
    GEMM_T(Wm, xs, skip); REDS(bias, src, dst, t1, k, sdst, skip, ~0u);
  };
  auto GNS = [&](const float* Wm, int xs, const float* bias, const float* src, float* dst,
                 int t1, Key k, int sdst, const u32* skip) {
    GEMM_N(Wm, xs, skip); REDS(bias, src, dst, t1, k, sdst, skip, ~0u);
  };
  auto SAMP = [&](const float* fE, const float* fO, u32 even, int t1, Key k, int dst) {
    k_samp<<<dim3(768), dim3(256), 0, stream>>>(fE, fO, even, t1, k.a, k.b, PK[dst]);
  };
  auto BERN = [&](Key k, int dst) {
    k_bern<<<dim3(768), dim3(256), 0, stream>>>(k.a, k.b, PK[dst]);
  };
  auto ENERGY = [&](int sv, int sh0, int sh1, const float* f1, const float* f2, float* eo, const u32* skip) {
    k_energy<<<dim3(32), dim3(256), 0, stream>>>(PK[sv], PK[sh0], PK[sh1], f1, f2, b0, eo, skip);
  };

  // ===== staggered T=0 local search (round-7-proven structure) =====
  // pos (fixv): X: h1 <- samp(h0@W1.T + b2) [masked rows]; Y: h0 <- samp(fv + h1@W1) [all rows]
  auto ls_fixv = [&](u32 evm) {
    auto X = [&](u32 wm) {
      GEMM_T(W1, SH0, nullptr);
      REDS(b2, nullptr, nullptr, 0, KZ, SH1, nullptr, wm);
    };
    auto Y = [&]() {
      GEMM_N(W1, SH1, nullptr);
      REDS(nullptr, F[IV], nullptr, 0, KZ, SH0, nullptr, ~0u);
    };
    X(evm);
    for (int i = 0; i < 31; ++i) { Y(); X(~0u); }
    Y(); X(~evm);
  };
  // neg (free): X: v <- samp(h0@W0+b0), h1 <- samp(h0@W1.T+b2) [masked];
  //             Y: h0 <- samp(f32(f32(v@W0.T+b1) + h1@W1)) [all]
  auto ls_free = [&](u32 evm) {
    auto X = [&](u32 wm) {
      GEMM_N(W0, SH0, nullptr);
      REDS(b0, nullptr, nullptr, 0, KZ, SV, nullptr, wm);
      GEMM_T(W1, SH0, nullptr);
      REDS(b2, nullptr, nullptr, 0, KZ, SH1, nullptr, wm);
    };
    auto Y = [&]() {
      GT(W0, SV, b1, nullptr, F[IC], nullptr);
      GEMM_N(W1, SH1, nullptr);
      REDS(nullptr, F[IC], nullptr, 0, KZ, SH0, nullptr, ~0u);
    };
    X(evm);
    for (int i = 0; i < 31; ++i) { Y(); X(~0u); }
    Y(); X(~evm);
  };

  // ===== T=1 gibbs steps =====
  auto gibbs_fixv = [&](u32 even, Key kh0, Key kh1) {
    GTS(W1, SH0, b2, nullptr, F[IA], 1, kh1, SH1E, nullptr);     // f_h1e ; h1_e
    GN(W1, SH1E, nullptr, F[IV], F[IB], nullptr);                // f_h0e = fv + h1_e@W1
    GNS(W1, SH1, nullptr, F[IV], F[IC], 1, kh0, SH0O, nullptr);  // f_h0o ; h0_o
    GT(W1, SH0O, b2, nullptr, F[ID], nullptr);                   // f_h1o
    SAMP(F[IB], F[IC], even, 1, kh0, SH0);                       // h0 merge
    SAMP(F[IA], F[ID], even, 1, kh1, SH1);                       // h1 merge
  };
  auto gibbs_free = [&](u32 even, Key kv, Key kh0, Key kh1) {
    GNS(W0, SH0, b0, nullptr, F[IE], 1, kv, SVE, nullptr);       // f_ve ; v_e
    GTS(W1, SH0, b2, nullptr, F[IA], 1, kh1, SH1E, nullptr);     // f_h1e ; h1_e
    GT(W0, SVE, b1, nullptr, F[IB], nullptr);                    // f_h0e = v_e@W0.T + b1
    GN(W1, SH1E, nullptr, F[IB], F[IB], nullptr);                //        + h1_e@W1
    GT(W0, SV, b1, nullptr, F[IC], nullptr);                     // f_h0o = v@W0.T + b1
    GNS(W1, SH1, nullptr, F[IC], F[IC], 1, kh0, SH0O, nullptr);  //        + h1@W1 ; h0_o
    GN(W0, SH0O, b0, nullptr, F[IF2], nullptr);                  // f_vo
    GT(W1, SH0O, b2, nullptr, F[ID], nullptr);                   // f_h1o
    SAMP(F[IE], F[IF2], even, 1, kv, SV);                        // v merge
    SAMP(F[IB], F[IC], even, 1, kh0, SH0);                       // h0 merge
    SAMP(F[IA], F[ID], even, 1, kh1, SH1);                       // h1 merge
  };

  // ===== coupling; E_CUR holds energy(cur); fixv uses F[IV]=fv; all-conv skips rest =====
  auto coupling = [&](bool fixv, Key ck, float* erun) {
    Key top[2]; split_keys(ck, 2, top);
    Key cks[17]; cks[0] = top[0];
    { Key rest[16]; split_keys(top[1], 16, rest); for (int i = 0; i < 16; ++i) cks[i + 1] = rest[i]; }
    k_init<<<dim3(1), dim3(1), 0, stream>>>(SKIPC, DUMMY);
    for (int it = 0; it < 17; ++it) {
      const u32* sk = (it == 0) ? nullptr : SKIPC;
      Key sub[4]; split_keys(cks[it], 4, sub);        // kv, kh0, kh1, ku
      UVec uv;
      for (int b = 0; b < NB; ++b) uv.u[b] = u01f(rbits(sub[3].a, sub[3].b, (u32)b, HALF_SMALL));
      k_bern3<<<dim3(768), dim3(256), 0, stream>>>(fixv ? 0u : 1u,
          sub[0].a, sub[0].b, sub[1].a, sub[1].b, sub[2].a, sub[2].b,
          PK[SVP], PK[SH0P], PK[SH1P], sk);
      const float* f1;
      if (fixv) f1 = F[IV];
      else { GT(W0, SVP, b1, nullptr, F[IC], sk); f1 = F[IC]; }
      GT(W1, SH0P, b2, nullptr, F[ID], sk);
      ENERGY(fixv ? SV : SVP, SH0P, SH1P, f1, F[ID], E_PROP, sk);
      k_accept<<<dim3(32), dim3(64), 0, stream>>>(E_CUR, E_PROP, erun, CONV, ACC,
          fixv ? nullptr : PK[SVP], fixv ? nullptr : PK[SV],
          PK[SH0P], PK[SH0], PK[SH1P], PK[SH1], uv, it == 0 ? 1 : 0, sk);
      k_merge_pk<<<dim3(12), dim3(256), 0, stream>>>(ACC, PK[SH0P], PK[SH0], PK[SH1P], PK[SH1],
          fixv ? nullptr : PK[SVP], fixv ? nullptr : PK[SV], sk);
      k_allconv<<<dim3(1), dim3(1), 0, stream>>>(CONV, SKIPC);
    }
  };

  // ================= positive phase =================
  k_pos_v<<<dim3(96), dim3(256), 0, stream>>>(vin, PK[SV]);
  BERN(ks[0], SH0);
  BERN(ks[1], SH1);
  GT(W0, SV, b1, nullptr, F[IV], nullptr);            // fv = v@W0.T + b1 (constant in pos phase)
  u32 ev_ls_pos = mask32(ks[2]);
  ls_fixv(ev_ls_pos);
  u32 ev2_pos = mask32(ks[3]);
  Key g4[3]; split_keys(ks[4], 3, g4);                // kv(unused), kh0, kh1
  gibbs_fixv(ev2_pos, g4[1], g4[2]);
  GT(W1, SH0, b2, nullptr, F[ID], nullptr);           // f2 for energy(cur)
  ENERGY(SV, SH0, SH1, F[IV], F[ID], E_CUR, nullptr);
  coupling(true, ks[5], E_POS);

  // ================= negative phase =================
  BERN(ks[6], SV);
  BERN(ks[7], SH0);
  BERN(ks[8], SH1);
  u32 ev_ls_neg = mask32(ks[9]);
  ls_free(ev_ls_neg);
  u32 ev2_neg = mask32(ks[10]);
  Key g11[3]; split_keys(ks[11], 3, g11);
  gibbs_free(ev2_neg, g11[0], g11[1], g11[2]);
  GT(W0, SV, b1, nullptr, F[IB], nullptr);            // f1 for energy(cur)
  GT(W1, SH0, b2, nullptr, F[IA], nullptr);           // f2
  ENERGY(SV, SH0, SH1, F[IB], F[IA], E_CUR, nullptr);
  coupling(false, ks[12], E_NEG);

  k_final<<<dim3(1), dim3(64), 0, stream>>>(E_POS, E_NEG, outp);
}

// Round 16
// 11977.449 us; speedup vs baseline: 1.0421x; 1.0421x over previous
//
#include <hip/hip_runtime.h>
#include <cstdint>
#include <math.h>

typedef unsigned int u32;
typedef unsigned long long u64;
typedef double d4 __attribute__((ext_vector_type(4)));

#define TF_PARTITIONABLE 1

#define NU 6144
#define NB 32
#define NTOT (NU * NB)      // 196608
#define NWORD 96            // u64 words per sample row
#define NCH 16              // split-K chunks per GEMM (grid 1536 = 6 blocks/CU)
#define CHK 384             // k per chunk; 6 u64 words per row-chunk
#define NT_TILES 12         // CHK / 32
#define HALF_BIG 98304u
#define HALF_SMALL 16u

struct Key { u32 a, b; };
struct UVec { float u[NB]; };

// ---------------- threefry2x32 (20 rounds), matches jax._src.prng ----------------
__host__ __device__ __forceinline__ void tf2x32(u32 k0, u32 k1, u32 x0, u32 x1, u32& o0, u32& o1) {
  const u32 k2 = k0 ^ k1 ^ 0x1BD11BDAu;
#define TFR(r) { x0 += x1; x1 = (x1 << r) | (x1 >> (32 - r)); x1 ^= x0; }
  x0 += k0; x1 += k1;
  TFR(13) TFR(15) TFR(26) TFR(6)  x0 += k1; x1 += k2 + 1u;
  TFR(17) TFR(29) TFR(16) TFR(24) x0 += k2; x1 += k0 + 2u;
  TFR(13) TFR(15) TFR(26) TFR(6)  x0 += k0; x1 += k1 + 3u;
  TFR(17) TFR(29) TFR(16) TFR(24) x0 += k1; x1 += k2 + 4u;
  TFR(13) TFR(15) TFR(26) TFR(6)  x0 += k2; x1 += k0 + 5u;
#undef TFR
  o0 = x0; o1 = x1;
}

__host__ __device__ __forceinline__ u32 rbits(u32 k0, u32 k1, u32 t, u32 half) {
#if TF_PARTITIONABLE
  (void)half;
  u32 a, b; tf2x32(k0, k1, 0u, t, a, b); return a ^ b;
#else
  u32 a, b;
  if (t < half) { tf2x32(k0, k1, t, half + t, a, b); return a; }
  tf2x32(k0, k1, t - half, t, a, b); return b;
#endif
}

__host__ __device__ __forceinline__ float u01f(u32 bits) {
  union { u32 u; float f; } c; c.u = (bits >> 9) | 0x3f800000u;
  return c.f - 1.0f;
}

// ---------------- MFMA f64 layout self-calibration ----------------
__device__ __forceinline__ double pav(int probe, int l) {
  return probe ? (double)(((l * 13 + 5) & 63) + 1) : (double)(l + 1);
}
__device__ __forceinline__ double pbv(int probe, int l) {
  return probe ? (double)(((l * 11 + 2) & 63) + 1) : (double)(((l * 7 + 3) & 63) + 1);
}

// tbl[lane*16 + {0..8}] = mA,kA,nB,kB,bD0,bDs,jD0,jDs,ok
__global__ __launch_bounds__(64) void k_calib(int* __restrict__ tbl) {
  int L = threadIdx.x;
  d4 z = {0.0, 0.0, 0.0, 0.0};
  d4 o0 = __builtin_amdgcn_mfma_f64_16x16x4f64(pav(0, L), pbv(0, L), z, 0, 0, 0);
  d4 o1 = __builtin_amdgcn_mfma_f64_16x16x4f64(pav(1, L), pbv(1, L), z, 0, 0, 0);
  int q = L >> 4, m16 = L & 15;
  int best = -1;
  for (int combo = 0; combo < 16; ++combo) {
    int fa = combo & 1, fb = (combo >> 1) & 1, fd = combo >> 2;
    int ok = 1;
    for (int probe = 0; probe < 2; ++probe) {
#pragma unroll
      for (int r = 0; r < 4; ++r) {
        int i, j;
        if (fd == 0)      { j = m16; i = 4 * q + r; }
        else if (fd == 1) { j = m16; i = q + 4 * r; }
        else if (fd == 2) { i = m16; j = 4 * q + r; }
        else              { i = m16; j = q + 4 * r; }
        double pred = 0.0;
#pragma unroll
        for (int k = 0; k < 4; ++k) {
          int la = fa ? (i * 4 + k) : (k * 16 + i);
          int lb = fb ? (j * 4 + k) : (k * 16 + j);
          pred += pav(probe, la) * pbv(probe, lb);
        }
        double obs = probe ? (r == 0 ? o1[0] : r == 1 ? o1[1] : r == 2 ? o1[2] : o1[3])
                           : (r == 0 ? o0[0] : r == 1 ? o0[1] : r == 2 ? o0[2] : o0[3]);
        if (pred != obs) ok = 0;
      }
    }
    if (__all(ok) && best < 0) best = combo;
  }
  int mA = 0, kA = 0, nB = 0, kB = 0, b0_ = 0, bs = 0, j0 = 0, js = 0, okf = 0;
  if (best >= 0) {
    int fa = best & 1, fb = (best >> 1) & 1, fd = best >> 2;
    if (fa) { mA = L >> 2; kA = L & 3; } else { mA = m16; kA = q; }
    if (fb) { nB = L >> 2; kB = L & 3; } else { nB = m16; kB = q; }
    if (fd == 0)      { j0 = m16; js = 0; b0_ = 4 * q; bs = 1; }
    else if (fd == 1) { j0 = m16; js = 0; b0_ = q; bs = 4; }
    else if (fd == 2) { b0_ = m16; bs = 0; j0 = 4 * q; js = 1; }
    else              { b0_ = m16; bs = 0; j0 = q; js = 4; }
    okf = 1;
  }
  int* p = tbl + L * 16;
  p[0] = mA; p[1] = kA; p[2] = nB; p[3] = kB;
  p[4] = b0_; p[5] = bs; p[6] = j0; p[7] = js; p[8] = okf;
}

// ---------------- control kernels ----------------
__global__ void k_init(u32* __restrict__ a, u32* __restrict__ b) { *a = 0u; *b = 0u; }

__global__ void k_allconv(const u32* __restrict__ conv, u32* __restrict__ skipc) {
  if (*skipc) return;
  u32 all = 1u;
  for (int b = 0; b < NB; ++b) all &= conv[b];
  if (all) *skipc = 1u;
}

// ---------------- state init (bit-packed only; states live in pk) ----------------
__global__ __launch_bounds__(256) void k_pos_v(const float* __restrict__ vin, u64* __restrict__ pk) {
  int tid = blockIdx.x * 256 + threadIdx.x;          // 24576 = 32*768
  int b = tid / 768, p = tid % 768;
  float x = vin[tid];
  int q = (int)floorf(x * 256.0f);
  q = q < 0 ? 0 : (q > 255 ? 255 : q);
  ((unsigned char*)pk)[b * 768 + p] = (unsigned char)q;   // byte == 8 LSB-first bits
}

__global__ __launch_bounds__(256) void k_bern(u32 k0, u32 k1, u64* __restrict__ pk) {
  int tid = blockIdx.x * 256 + threadIdx.x;          // 196608
  bool s = u01f(rbits(k0, k1, (u32)tid, HALF_BIG)) < 0.5f;
  u64 m = __ballot(s);
  if ((threadIdx.x & 63) == 0) pk[tid >> 6] = m;
}

// fused proposal generator for coupling (2 or 3 states, one dispatch)
__global__ __launch_bounds__(256) void k_bern3(u32 has_v, u32 va, u32 vb, u32 ha0, u32 hb0,
                                               u32 ha1, u32 hb1,
                                               u64* __restrict__ pkv, u64* __restrict__ pkh0,
                                               u64* __restrict__ pkh1, const u32* __restrict__ skip) {
  if (skip && *skip) return;
  int tid = blockIdx.x * 256 + threadIdx.x;
  int lane0 = (threadIdx.x & 63) == 0;
  if (has_v) {
    bool s = u01f(rbits(va, vb, (u32)tid, HALF_BIG)) < 0.5f;
    u64 m = __ballot(s);
    if (lane0) pkv[tid >> 6] = m;
  }
  { bool s = u01f(rbits(ha0, hb0, (u32)tid, HALF_BIG)) < 0.5f;
    u64 m = __ballot(s);
    if (lane0) pkh0[tid >> 6] = m; }
  { bool s = u01f(rbits(ha1, hb1, (u32)tid, HALF_BIG)) < 0.5f;
    u64 m = __ballot(s);
    if (lane0) pkh1[tid >> 6] = m; }
}

// ---------------- sampling ----------------
__device__ __forceinline__ bool samp_dec(float f, int t1, u32 k0, u32 k1, u32 tid) {
  if (t1) {
    double u = (double)u01f(rbits(k0, k1, tid, HALF_BIG));
    return u < 1.0 / (1.0 + exp(-(double)f));
  }
  return f >= 0.0f;
}

// merged sample over even mask (T=1 gibbs merges); writes pk only
__global__ __launch_bounds__(256) void k_samp(const float* __restrict__ fE, const float* __restrict__ fO,
                                              u32 even, int t1, u32 k0, u32 k1,
                                              u64* __restrict__ pk) {
  int tid = blockIdx.x * 256 + threadIdx.x;
  int b = tid / NU;
  float f = ((even >> b) & 1u) ? fE[tid] : fO[tid];
  bool s = samp_dec(f, t1, k0, k1, (u32)tid);
  u64 m = __ballot(s);
  if ((threadIdx.x & 63) == 0) pk[tid >> 6] = m;
}

// ---------------- GEMM kernels: barrier-free, LDS-free; x bits + W direct loads ----------------
// out[b][j] = sum_k x[k][b] * W[k][j]  (x @ W).  k(slot kappa, step u) = base + kappa + 4u.
__global__ __launch_bounds__(256) void k_gemm_n(const float* __restrict__ W, const u64* __restrict__ pkx,
                                                double* __restrict__ part, const u32* __restrict__ skip,
                                                const int* __restrict__ tbl) {
  if (skip && *skip) return;
  int jt = blockIdx.x % 96, c = blockIdx.x / 96;     // grid 96*NCH
  int wid = threadIdx.x >> 6, lane = threadIdx.x & 63;
  int kbase = c * CHK;
  int jn0 = jt * 64;
  const int* tp = tbl + lane * 16;
  if (tp[8]) {
    int mA = tp[0], kA = tp[1], nB = tp[2], kB = tp[3];
    int bD0 = tp[4], bDs = tp[5], jD0 = tp[6], jDs = tp[7];
    d4 acc0 = {0.0, 0.0, 0.0, 0.0};
    d4 acc1 = {0.0, 0.0, 0.0, 0.0};
    const u64* px0 = pkx + (size_t)mA * NWORD + (kbase >> 6);
    const u64* px1 = pkx + (size_t)(mA + 16) * NWORD + (kbase >> 6);
    u64 xw0[6], xw1[6];
#pragma unroll
    for (int i = 0; i < 6; ++i) { xw0[i] = px0[i]; xw1[i] = px1[i]; }
    const float* wb = W + (size_t)(kbase + kB) * NU + jn0 + wid * 16 + nB;
    float cur[8], nxt[8];
#pragma unroll
    for (int u = 0; u < 8; ++u) cur[u] = wb[(size_t)(4 * u) * NU];
    for (int t = 0; t < NT_TILES; ++t) {
      if (t + 1 < NT_TILES) {
        const float* wn = wb + (size_t)((t + 1) * 32) * NU;
#pragma unroll
        for (int u = 0; u < 8; ++u) nxt[u] = wn[(size_t)(4 * u) * NU];
      }
      u32 bb0 = (u32)(xw0[t >> 1] >> (((t & 1) << 5) + kA));
      u32 bb1 = (u32)(xw1[t >> 1] >> (((t & 1) << 5) + kA));
#pragma unroll
      for (int u = 0; u < 8; ++u) {
        double wv = (double)cur[u];
        double a0 = (double)((bb0 >> (4 * u)) & 1u);
        double a1 = (double)((bb1 >> (4 * u)) & 1u);
        acc0 = __builtin_amdgcn_mfma_f64_16x16x4f64(a0, wv, acc0, 0, 0, 0);
        acc1 = __builtin_amdgcn_mfma_f64_16x16x4f64(a1, wv, acc1, 0, 0, 0);
      }
#pragma unroll
      for (int u = 0; u < 8; ++u) cur[u] = nxt[u];
    }
    int jn = jn0 + wid * 16;
    double* pp = part + (size_t)c * NTOT + jn;
#pragma unroll
    for (int r = 0; r < 4; ++r) {
      int bi = bD0 + bDs * r, jj = jD0 + jDs * r;
      pp[(size_t)bi * NU + jj] = acc0[r];
      pp[(size_t)(bi + 16) * NU + jj] = acc1[r];
    }
  } else {
    // LDS-free VALU fallback (dead path): wave wid = batch group (8 b), full chunk
    int j = jn0 + lane;
    const float* wp = W + (size_t)kbase * NU + j;
    double acc[8];
#pragma unroll
    for (int b = 0; b < 8; ++b) acc[b] = 0.0;
    for (int i = 0; i < CHK; ++i) {
      double w = (double)wp[(size_t)i * NU];
      int k = kbase + i;
#pragma unroll
      for (int b = 0; b < 8; ++b) {
        double xb = (double)((pkx[(size_t)(wid * 8 + b) * NWORD + (k >> 6)] >> (k & 63)) & 1ull);
        acc[b] = fma(xb, w, acc[b]);
      }
    }
    double* pp = part + (size_t)c * NTOT + j;
#pragma unroll
    for (int b = 0; b < 8; ++b) pp[(size_t)(wid * 8 + b) * NU] = acc[b];
  }
}

// out[b][j] = sum_k x[k][b] * W[j][k]  (x @ W.T).  k(slot kappa, step u) = base + kappa*8 + u.
__global__ __launch_bounds__(256) void k_gemm_t(const float* __restrict__ W, const u64* __restrict__ pkx,
                                                double* __restrict__ part, const u32* __restrict__ skip,
                                                const int* __restrict__ tbl) {
  if (skip && *skip) return;
  int jt = blockIdx.x % 96, c = blockIdx.x / 96;
  int wid = threadIdx.x >> 6, lane = threadIdx.x & 63;
  int kbase = c * CHK;
  int jn0 = jt * 64;
  const int* tp = tbl + lane * 16;
  if (tp[8]) {
    int mA = tp[0], kA = tp[1], nB = tp[2], kB = tp[3];
    int bD0 = tp[4], bDs = tp[5], jD0 = tp[6], jDs = tp[7];
    d4 acc0 = {0.0, 0.0, 0.0, 0.0};
    d4 acc1 = {0.0, 0.0, 0.0, 0.0};
    const u64* px0 = pkx + (size_t)mA * NWORD + (kbase >> 6);
    const u64* px1 = pkx + (size_t)(mA + 16) * NWORD + (kbase >> 6);
    u64 xw0[6], xw1[6];
#pragma unroll
    for (int i = 0; i < 6; ++i) { xw0[i] = px0[i]; xw1[i] = px1[i]; }
    const float* wb = W + (size_t)(jn0 + wid * 16 + nB) * NU + kbase + kB * 8;
    float4 c0 = *(const float4*)(wb);
    float4 c1 = *(const float4*)(wb + 4);
    for (int t = 0; t < NT_TILES; ++t) {
      float4 n0, n1;
      if (t + 1 < NT_TILES) {
        const float* wn = wb + (t + 1) * 32;
        n0 = *(const float4*)(wn);
        n1 = *(const float4*)(wn + 4);
      }
      u32 bb0 = (u32)(xw0[t >> 1] >> (((t & 1) << 5) + kA * 8));
      u32 bb1 = (u32)(xw1[t >> 1] >> (((t & 1) << 5) + kA * 8));
      float fr0 = c0.x, fr1 = c0.y, fr2 = c0.z, fr3 = c0.w;
      float fr4 = c1.x, fr5 = c1.y, fr6 = c1.z, fr7 = c1.w;
#pragma unroll
      for (int u = 0; u < 8; ++u) {
        float fv = (u == 0) ? fr0 : (u == 1) ? fr1 : (u == 2) ? fr2 : (u == 3) ? fr3
                 : (u == 4) ? fr4 : (u == 5) ? fr5 : (u == 6) ? fr6 : fr7;
        double wv = (double)fv;
        double a0 = (double)((bb0 >> u) & 1u);
        double a1 = (double)((bb1 >> u) & 1u);
        acc0 = __builtin_amdgcn_mfma_f64_16x16x4f64(a0, wv, acc0, 0, 0, 0);
        acc1 = __builtin_amdgcn_mfma_f64_16x16x4f64(a1, wv, acc1, 0, 0, 0);
      }
      c0 = n0; c1 = n1;
    }
    int jn = jn0 + wid * 16;
    double* pp = part + (size_t)c * NTOT + jn;
#pragma unroll
    for (int r = 0; r < 4; ++r) {
      int bi = bD0 + bDs * r, jj = jD0 + jDs * r;
      pp[(size_t)bi * NU + jj] = acc0[r];
      pp[(size_t)(bi + 16) * NU + jj] = acc1[r];
    }
  } else {
    // LDS-free VALU fallback (dead path): wave wid = batch group, scalar W[j][k] reads
    int j = jn0 + lane;
    const float* wp = W + (size_t)j * NU + kbase;
    double acc[8];
#pragma unroll
    for (int b = 0; b < 8; ++b) acc[b] = 0.0;
    for (int i = 0; i < CHK; ++i) {
      double w = (double)wp[i];
      int k = kbase + i;
#pragma unroll
      for (int b = 0; b < 8; ++b) {
        double xb = (double)((pkx[(size_t)(wid * 8 + b) * NWORD + (k >> 6)] >> (k & 63)) & 1ull);
        acc[b] = fma(xb, w, acc[b]);
      }
    }
    double* pp = part + (size_t)c * NTOT + j;
#pragma unroll
    for (int b = 0; b < 8; ++b) pp[(size_t)(wid * 8 + b) * NU] = acc[b];
  }
}

// ---------------- reduce (+ optional fused sample) ----------------
__global__ __launch_bounds__(256) void k_reduce(const double* __restrict__ part, const float* __restrict__ bias,
                                                const float* __restrict__ src, float* __restrict__ out,
                                                const u32* __restrict__ skip) {
  if (skip && *skip) return;
  int tid = blockIdx.x * 256 + threadIdx.x;
  int j = tid % NU;
  double s = src ? (double)src[tid] : 0.0;
  if (bias) s += (double)bias[j];
#pragma unroll
  for (int c = 0; c < NCH; ++c) s += part[(size_t)c * NTOT + tid];
  out[tid] = (float)s;
}

// reduce -> (optional out); sample into pk for batch rows in wmask
__global__ __launch_bounds__(256) void k_redsamp(const double* __restrict__ part, const float* __restrict__ bias,
                                                 const float* __restrict__ src, float* __restrict__ out,
                                                 int t1, u32 k0, u32 k1,
                                                 u64* __restrict__ pk,
                                                 const u32* __restrict__ skip, u32 wmask) {
  if (skip && *skip) return;
  int tid = blockIdx.x * 256 + threadIdx.x;
  int j = tid % NU, b = tid / NU;
  double s = src ? (double)src[tid] : 0.0;
  if (bias) s += (double)bias[j];
#pragma unroll
  for (int c = 0; c < NCH; ++c) s += part[(size_t)c * NTOT + tid];
  float f = (float)s;
  if (out) out[tid] = f;
  bool wr = (wmask >> b) & 1u;
  bool smp = samp_dec(f, t1, k0, k1, (u32)tid);
  u64 m = __ballot(smp);
  if (((threadIdx.x & 63) == 0) && wr) pk[tid >> 6] = m;
  (void)j;
}

// ---------------- energy / accept / merge ----------------
__global__ __launch_bounds__(256) void k_energy(const u64* __restrict__ pkv, const u64* __restrict__ pkh0,
                                                const u64* __restrict__ pkh1, const float* __restrict__ f1,
                                                const float* __restrict__ f2, const float* __restrict__ b0,
                                                float* __restrict__ eout, const u32* __restrict__ skip) {
  if (skip && *skip) return;
  __shared__ double red[256];
  int b = blockIdx.x, t = threadIdx.x;
  double s = 0.0;
  for (int j = t; j < NU; j += 256) {
    int w = j >> 6, bit = j & 63;
    if ((pkv [b * NWORD + w] >> bit) & 1ull) s += (double)b0[j];
    if ((pkh0[b * NWORD + w] >> bit) & 1ull) s += (double)f1[(size_t)b * NU + j];
    if ((pkh1[b * NWORD + w] >> bit) & 1ull) s += (double)f2[(size_t)b * NU + j];
  }
  red[t] = s; __syncthreads();
  for (int off = 128; off > 0; off >>= 1) { if (t < off) red[t] += red[t + off]; __syncthreads(); }
  if (t == 0) eout[b] = (float)(-red[0]);
}

__global__ __launch_bounds__(64) void k_accept(float* __restrict__ ecur, const float* __restrict__ eprop,
                                               float* __restrict__ erun, u32* __restrict__ conv,
                                               u32* __restrict__ accf,
                                               const u64* __restrict__ pv, const u64* __restrict__ pcv,
                                               const u64* __restrict__ ph0, const u64* __restrict__ pch0,
                                               const u64* __restrict__ ph1, const u64* __restrict__ pch1,
                                               UVec uv, int first, const u32* __restrict__ skip) {
  if (skip && *skip) return;
  int b = blockIdx.x, t = threadIdx.x;
  u64 diff = 0ull;
  for (int w = t; w < NWORD; w += 64) {
    size_t o = (size_t)b * NWORD + w;
    if (pv) diff |= pv[o] ^ pcv[o];
    diff |= ph0[o] ^ pch0[o];
    diff |= ph1[o] ^ pch1[o];
  }
  int neq = __any(diff != 0ull);
  if (t == 0) {
    float ec = ecur[b], ep = eprop[b];
    bool acc = (double)uv.u[b] < exp(fmin((double)ec - (double)ep, 0.0));
    bool m = first ? true : (conv[b] == 0u);
    bool upd = m && acc;
    if (first) erun[b] = acc ? ep : ec;
    else if (upd) erun[b] += (ep - ec);
    if (upd) ecur[b] = ep;
    u32 c2 = acc ? (neq ? 0u : 1u) : 1u;
    conv[b] = first ? c2 : (conv[b] | c2);
    accf[b] = upd ? 1u : 0u;
  }
}

__global__ __launch_bounds__(256) void k_merge_pk(const u32* __restrict__ accf,
                                                  const u64* __restrict__ pa, u64* __restrict__ ca,
                                                  const u64* __restrict__ pb, u64* __restrict__ cb,
                                                  const u64* __restrict__ pc, u64* __restrict__ cc,
                                                  const u32* __restrict__ skip) {
  if (skip && *skip) return;
  int w = blockIdx.x * 256 + threadIdx.x;
  if (w >= NB * NWORD) return;
  int b = w / NWORD;
  if (accf[b]) {
    ca[w] = pa[w];
    cb[w] = pb[w];
    if (pc) cc[w] = pc[w];
  }
}

__global__ void k_final(const float* __restrict__ ep, const float* __restrict__ en, float* __restrict__ out) {
  int b = threadIdx.x;
  if (b < NB) out[b] = ep[b] - en[b];
}

// ---------------- host-side key derivation ----------------
static void split_keys(Key k, int n, Key* out) {
#if TF_PARTITIONABLE
  for (int i = 0; i < n; ++i) { u32 a, b; tf2x32(k.a, k.b, 0u, (u32)i, a, b); out[i].a = a; out[i].b = b; }
#else
  u32 flat[64];
  for (int i = 0; i < n; ++i) { u32 a, b; tf2x32(k.a, k.b, (u32)i, (u32)(n + i), a, b); flat[i] = a; flat[n + i] = b; }
  for (int i = 0; i < n; ++i) { out[i].a = flat[2 * i]; out[i].b = flat[2 * i + 1]; }
#endif
}
static u32 mask32(Key k) {
  u32 m = 0;
  for (int b = 0; b < NB; ++b)
    if (u01f(rbits(k.a, k.b, (u32)b, HALF_SMALL)) < 0.5f) m |= (1u << b);
  return m;
}

extern "C" void kernel_launch(void* const* d_in, const int* in_sizes, int n_in,
                              void* d_out, int out_size, void* d_ws, size_t ws_size,
                              hipStream_t stream) {
  const float* vin = (const float*)d_in[0];
  const float* W0  = (const float*)d_in[1];
  const float* W1  = (const float*)d_in[2];
  const float* b0  = (const float*)d_in[3];
  const float* b1  = (const float*)d_in[4];
  const float* b2  = (const float*)d_in[5];
  float* outp = (float*)d_out;

  // ---- workspace layout (~31 MB) ----
  char* ws = (char*)d_ws;
  size_t off = 0;
  auto alloc = [&](size_t bytes) -> void* {
    void* p = ws + off; off += (bytes + 255) & ~(size_t)255; return p;
  };
  enum { SV = 0, SH0, SH1, SVE, SH1E, SH0O, SVP, SH0P, SH1P, NS };
  enum { IV = 0, IA, IB, IC, ID, IE, IF2, NF };
  u64* PK[NS]; float* F[NF];
  for (int f = 0; f < NF; ++f) F[f] = (float*)alloc((size_t)NTOT * 4);
  double* PART = (double*)alloc((size_t)NCH * NTOT * 8);
  for (int s = 0; s < NS; ++s) PK[s] = (u64*)alloc((size_t)NB * NWORD * 8);
  int*   TBL    = (int*)alloc(64 * 16 * 4);
  float* E_CUR  = (float*)alloc(256);
  float* E_PROP = (float*)alloc(256);
  float* E_POS  = (float*)alloc(256);
  float* E_NEG  = (float*)alloc(256);
  u32*   ACC    = (u32*)alloc(256);
  u32*   CONV   = (u32*)alloc(256);
  u32*   SKIPC  = (u32*)alloc(256);
  u32*   DUMMY  = (u32*)alloc(256);
  if (off > ws_size) return;

  // ---- host RNG: full key tree from jax.random.key(42) ----
  Key root{0u, 42u};
  Key ks[13]; split_keys(root, 13, ks);
  const Key KZ{0u, 0u};

  // ---- MFMA layout calibration (deterministic, graph-safe) ----
  k_calib<<<dim3(1), dim3(64), 0, stream>>>(TBL);

  // ---- launch helpers ----
  auto GEMM_T = [&](const float* Wm, int xs, const u32* skip) {
    k_gemm_t<<<dim3(96 * NCH), dim3(256), 0, stream>>>(Wm, PK[xs], PART, skip, TBL);
  };
  auto GEMM_N = [&](const float* Wm, int xs, const u32* skip) {
    k_gemm_n<<<dim3(96 * NCH), dim3(256), 0, stream>>>(Wm, PK[xs], PART, skip, TBL);
  };
  auto RED = [&](const float* bias, const float* src, float* dst, const u32* skip) {
    k_reduce<<<dim3(768), dim3(256), 0, stream>>>(PART, bias, src, dst, skip);
  };
  auto REDS = [&](const float* bias, const float* src, float* dst, int t1, Key k, int sdst,
                  const u32* skip, u32 wm) {
    k_redsamp<<<dim3(768), dim3(256), 0, stream>>>(PART, bias, src, dst, t1, k.a, k.b,
                                                   PK[sdst], skip, wm);
  };
  auto GT = [&](const float* Wm, int xs, const float* bias, const float* src, float* dst, const u32* skip) {
    GEMM_T(Wm, xs, skip); RED(bias, src, dst, skip);
  };
  auto GN = [&](const float* Wm, int xs, const float* bias, const float* src, float* dst, const u32* skip) {
    GEMM_N(Wm, xs, skip); RED(bias, src, dst, skip);
  };
  auto GTS = [&](const float* Wm, int xs, const float* bias, const float* src, float* dst,
                 int t1, Key k, int sdst, const u32* skip) {
    GEMM_T(Wm, xs, skip); REDS(bias, src, dst, t1, k, sdst, skip, ~0u);
  };
  auto GNS = [&](const float* Wm, int xs, const float* bias, const float* src, float* dst,
                 int t1, Key k, int sdst, const u32* skip) {
    GEMM_N(Wm, xs, skip); REDS(bias, src, dst, t1, k, sdst, skip, ~0u);
  };
  auto SAMP = [&](const float* fE, const float* fO, u32 even, int t1, Key k, int dst) {
    k_samp<<<dim3(768), dim3(256), 0, stream>>>(fE, fO, even, t1, k.a, k.b, PK[dst]);
  };
  auto BERN = [&](Key k, int dst) {
    k_bern<<<dim3(768), dim3(256), 0, stream>>>(k.a, k.b, PK[dst]);
  };
  auto ENERGY = [&](int sv, int sh0, int sh1, const float* f1, const float* f2, float* eo, const u32* skip) {
    k_energy<<<dim3(32), dim3(256), 0, stream>>>(PK[sv], PK[sh0], PK[sh1], f1, f2, b0, eo, skip);
  };

  // ===== staggered T=0 local search (round-7-proven structure) =====
  // pos (fixv): X: h1 <- samp(h0@W1.T + b2) [masked rows]; Y: h0 <- samp(fv + h1@W1) [all rows]
  auto ls_fixv = [&](u32 evm) {
    auto X = [&](u32 wm) {
      GEMM_T(W1, SH0, nullptr);
      REDS(b2, nullptr, nullptr, 0, KZ, SH1, nullptr, wm);
    };
    auto Y = [&]() {
      GEMM_N(W1, SH1, nullptr);
      REDS(nullptr, F[IV], nullptr, 0, KZ, SH0, nullptr, ~0u);
    };
    X(evm);
    for (int i = 0; i < 31; ++i) { Y(); X(~0u); }
    Y(); X(~evm);
  };
  // neg (free): X: v <- samp(h0@W0+b0), h1 <- samp(h0@W1.T+b2) [masked];
  //             Y: h0 <- samp(f32(f32(v@W0.T+b1) + h1@W1)) [all]
  auto ls_free = [&](u32 evm) {
    auto X = [&](u32 wm) {
      GEMM_N(W0, SH0, nullptr);
      REDS(b0, nullptr, nullptr, 0, KZ, SV, nullptr, wm);
      GEMM_T(W1, SH0, nullptr);
      REDS(b2, nullptr, nullptr, 0, KZ, SH1, nullptr, wm);
    };
    auto Y = [&]() {
      GT(W0, SV, b1, nullptr, F[IC], nullptr);
      GEMM_N(W1, SH1, nullptr);
      REDS(nullptr, F[IC], nullptr, 0, KZ, SH0, nullptr, ~0u);
    };
    X(evm);
    for (int i = 0; i < 31; ++i) { Y(); X(~0u); }
    Y(); X(~evm);
  };

  // ===== T=1 gibbs steps =====
  auto gibbs_fixv = [&](u32 even, Key kh0, Key kh1) {
    GTS(W1, SH0, b2, nullptr, F[IA], 1, kh1, SH1E, nullptr);     // f_h1e ; h1_e
    GN(W1, SH1E, nullptr, F[IV], F[IB], nullptr);                // f_h0e = fv + h1_e@W1
    GNS(W1, SH1, nullptr, F[IV], F[IC], 1, kh0, SH0O, nullptr);  // f_h0o ; h0_o
    GT(W1, SH0O, b2, nullptr, F[ID], nullptr);                   // f_h1o
    SAMP(F[IB], F[IC], even, 1, kh0, SH0);                       // h0 merge
    SAMP(F[IA], F[ID], even, 1, kh1, SH1);                       // h1 merge
  };
  auto gibbs_free = [&](u32 even, Key kv, Key kh0, Key kh1) {
    GNS(W0, SH0, b0, nullptr, F[IE], 1, kv, SVE, nullptr);       // f_ve ; v_e
    GTS(W1, SH0, b2, nullptr, F[IA], 1, kh1, SH1E, nullptr);     // f_h1e ; h1_e
    GT(W0, SVE, b1, nullptr, F[IB], nullptr);                    // f_h0e = v_e@W0.T + b1
    GN(W1, SH1E, nullptr, F[IB], F[IB], nullptr);                //        + h1_e@W1
    GT(W0, SV, b1, nullptr, F[IC], nullptr);                     // f_h0o = v@W0.T + b1
    GNS(W1, SH1, nullptr, F[IC], F[IC], 1, kh0, SH0O, nullptr);  //        + h1@W1 ; h0_o
    GN(W0, SH0O, b0, nullptr, F[IF2], nullptr);                  // f_vo
    GT(W1, SH0O, b2, nullptr, F[ID], nullptr);                   // f_h1o
    SAMP(F[IE], F[IF2], even, 1, kv, SV);                        // v merge
    SAMP(F[IB], F[IC], even, 1, kh0, SH0);                       // h0 merge
    SAMP(F[IA], F[ID], even, 1, kh1, SH1);                       // h1 merge
  };

  // ===== coupling; E_CUR holds energy(cur); fixv uses F[IV]=fv; all-conv skips rest =====
  auto coupling = [&](bool fixv, Key ck, float* erun) {
    Key top[2]; split_keys(ck, 2, top);
    Key cks[17]; cks[0] = top[0];
    { Key rest[16]; split_keys(top[1], 16, rest); for (int i = 0; i < 16; ++i) cks[i + 1] = rest[i]; }
    k_init<<<dim3(1), dim3(1), 0, stream>>>(SKIPC, DUMMY);
    for (int it = 0; it < 17; ++it) {
      const u32* sk = (it == 0) ? nullptr : SKIPC;
      Key sub[4]; split_keys(cks[it], 4, sub);        // kv, kh0, kh1, ku
      UVec uv;
      for (int b = 0; b < NB; ++b) uv.u[b] = u01f(rbits(sub[3].a, sub[3].b, (u32)b, HALF_SMALL));
      k_bern3<<<dim3(768), dim3(256), 0, stream>>>(fixv ? 0u : 1u,
          sub[0].a, sub[0].b, sub[1].a, sub[1].b, sub[2].a, sub[2].b,
          PK[SVP], PK[SH0P], PK[SH1P], sk);
      const float* f1;
      if (fixv) f1 = F[IV];
      else { GT(W0, SVP, b1, nullptr, F[IC], sk); f1 = F[IC]; }
      GT(W1, SH0P, b2, nullptr, F[ID], sk);
      ENERGY(fixv ? SV : SVP, SH0P, SH1P, f1, F[ID], E_PROP, sk);
      k_accept<<<dim3(32), dim3(64), 0, stream>>>(E_CUR, E_PROP, erun, CONV, ACC,
          fixv ? nullptr : PK[SVP], fixv ? nullptr : PK[SV],
          PK[SH0P], PK[SH0], PK[SH1P], PK[SH1], uv, it == 0 ? 1 : 0, sk);
      k_merge_pk<<<dim3(12), dim3(256), 0, stream>>>(ACC, PK[SH0P], PK[SH0], PK[SH1P], PK[SH1],
          fixv ? nullptr : PK[SVP], fixv ? nullptr : PK[SV], sk);
      k_allconv<<<dim3(1), dim3(1), 0, stream>>>(CONV, SKIPC);
    }
  };

  // ================= positive phase =================
  k_pos_v<<<dim3(96), dim3(256), 0, stream>>>(vin, PK[SV]);
  BERN(ks[0], SH0);
  BERN(ks[1], SH1);
  GT(W0, SV, b1, nullptr, F[IV], nullptr);            // fv = v@W0.T + b1 (constant in pos phase)
  u32 ev_ls_pos = mask32(ks[2]);
  ls_fixv(ev_ls_pos);
  u32 ev2_pos = mask32(ks[3]);
  Key g4[3]; split_keys(ks[4], 3, g4);                // kv(unused), kh0, kh1
  gibbs_fixv(ev2_pos, g4[1], g4[2]);
  GT(W1, SH0, b2, nullptr, F[ID], nullptr);           // f2 for energy(cur)
  ENERGY(SV, SH0, SH1, F[IV], F[ID], E_CUR, nullptr);
  coupling(true, ks[5], E_POS);

  // ================= negative phase =================
  BERN(ks[6], SV);
  BERN(ks[7], SH0);
  BERN(ks[8], SH1);
  u32 ev_ls_neg = mask32(ks[9]);
  ls_free(ev_ls_neg);
  u32 ev2_neg = mask32(ks[10]);
  Key g11[3]; split_keys(ks[11], 3, g11);
  gibbs_free(ev2_neg, g11[0], g11[1], g11[2]);
  GT(W0, SV, b1, nullptr, F[IB], nullptr);            // f1 for energy(cur)
  GT(W1, SH0, b2, nullptr, F[IA], nullptr);           // f2
  ENERGY(SV, SH0, SH1, F[IB], F[IA], E_CUR, nullptr);
  coupling(false, ks[12], E_NEG);

  k_final<<<dim3(1), dim3(64), 0, stream>>>(E_POS, E_NEG, outp);
}